// Round 17
// baseline (722.354 us; speedup 1.0000x reference)
//
#include <hip/hip_runtime.h>
#include <stdint.h>

typedef __attribute__((ext_vector_type(4))) int iv4;      // 4 VGPRs (16B)
typedef __attribute__((ext_vector_type(16))) int iv16;    // 16 VGPRs (acc)
typedef __attribute__((ext_vector_type(16))) char i8x16;

#define BM 256
#define BN 256
#define BKB 128   // K bytes per tile (i8); half-tile = [128 rows][128B] = 16KB

// ---- activation quantization: one block per row, per-row scale ----
__global__ __launch_bounds__(256) void quant_act(const float* __restrict__ in,
                                                 signed char* __restrict__ out,
                                                 float* __restrict__ s_a,
                                                 int K) {
  const int row = blockIdx.x;
  const int t = threadIdx.x;
  const float* a = in + (long)row * K;
  float4 v[4];
#pragma unroll
  for (int i = 0; i < 4; ++i)
    v[i] = reinterpret_cast<const float4*>(a)[t * 4 + i];
  float m = 0.f;
#pragma unroll
  for (int i = 0; i < 4; ++i) {
    m = fmaxf(m, fmaxf(fmaxf(fabsf(v[i].x), fabsf(v[i].y)),
                       fmaxf(fabsf(v[i].z), fabsf(v[i].w))));
  }
#pragma unroll
  for (int off = 32; off; off >>= 1) m = fmaxf(m, __shfl_xor(m, off));
  __shared__ float wmax[4];
  const int lane = t & 63, wvq = t >> 6;
  if (lane == 0) wmax[wvq] = m;
  __syncthreads();
  m = fmaxf(fmaxf(wmax[0], wmax[1]), fmaxf(wmax[2], wmax[3]));
  const float inv = m > 0.f ? 127.f / m : 0.f;
  if (t == 0) s_a[row] = m > 0.f ? m / 127.f : 0.f;
  i8x16 q;
#pragma unroll
  for (int i = 0; i < 4; ++i) {
    q[i * 4 + 0] = (char)(int)rintf(fminf(fmaxf(v[i].x * inv, -127.f), 127.f));
    q[i * 4 + 1] = (char)(int)rintf(fminf(fmaxf(v[i].y * inv, -127.f), 127.f));
    q[i * 4 + 2] = (char)(int)rintf(fminf(fmaxf(v[i].z * inv, -127.f), 127.f));
    q[i * 4 + 3] = (char)(int)rintf(fminf(fmaxf(v[i].w * inv, -127.f), 127.f));
  }
  reinterpret_cast<i8x16*>(out + (long)row * K)[t] = q;
}

// ---- weight pack: int32 (|v|<=127) -> int8 ----
__global__ void pack_w(const int* __restrict__ in, signed char* __restrict__ out,
                       long n16) {
  long stride = (long)gridDim.x * blockDim.x;
  for (long i = (long)blockIdx.x * blockDim.x + threadIdx.x; i < n16; i += stride) {
    i8x16 q;
#pragma unroll
    for (int c = 0; c < 4; ++c) {
      int4 w = reinterpret_cast<const int4*>(in)[i * 4 + c];
      q[c * 4 + 0] = (char)w.x;
      q[c * 4 + 1] = (char)w.y;
      q[c * 4 + 2] = (char)w.z;
      q[c * 4 + 3] = (char)w.w;
    }
    reinterpret_cast<i8x16*>(out)[i] = q;
  }
}

#define GLDS16(g, l)                                                          \
  __builtin_amdgcn_global_load_lds(                                           \
      (const __attribute__((address_space(1))) unsigned int*)(g),             \
      (__attribute__((address_space(3))) unsigned int*)(l), 16, 0, 0)

// Inline-asm ds_read_b128 (opaque to SIInsertWaitcnts; no clobbers in-loop
// so no hidden vmcnt(0) drains). rule #18: manual waits + sched_barrier(0).
typedef __attribute__((address_space(3))) const signed char lds_c8;

template <int OFF>
__device__ __forceinline__ iv4 ldsb128(lds_c8* p) {
  iv4 r;
  asm volatile("ds_read_b128 %0, %1 offset:%2" : "=v"(r) : "v"(p), "i"(OFF));
  return r;
}

#define BAR __builtin_amdgcn_s_barrier()
#define SCHEDB __builtin_amdgcn_sched_barrier(0)
#define LGKM_0 asm volatile("s_waitcnt lgkmcnt(0)")
#define LGKM_8 asm volatile("s_waitcnt lgkmcnt(8)")
#define VMC_4 asm volatile("s_waitcnt vmcnt(4)")

// 8 MFMAs for one C octant: 2 row-tiles (TI0,TI0+1) x 1 col-tile TJ x 4 ks
#define PH8(AA, BB, TI0, TJ)                                                  \
  _Pragma("unroll") for (int ks = 0; ks < 4; ++ks)                            \
    _Pragma("unroll") for (int t = 0; t < 2; ++t)                             \
      acc[(TI0) + t][TJ] = __builtin_amdgcn_mfma_i32_32x32x32_i8(             \
          AA[t][ks], BB[ks], acc[(TI0) + t][TJ], 0, 0, 0)

// 256x256 int8 GEMM — R16's m201 choreography unchanged; ONLY the MFMA shape
// swapped 16x16x64 -> 32x32x32 (4404 vs 3944 TOPS ubench; half the MFMA
// instruction count). Wave tile 128x64 = 4x2 tiles of 32x32; iv16 acc[4][2].
// Fragment: row=lane&31, k-bytes=(lane>>5)*16 (same analogy R14 HW-validated
// for 16x16 i8); ks-step in swizzled LDS = byte-XOR ks*32 (disjoint bits).
// Per-quarter LDS bank pattern identical to R16 (slot 0,0,1,1..7,7) -> 0 cfl.
__global__ __launch_bounds__(512, 2) void gemm256_m3(
    const signed char* __restrict__ A,   // [M][K] i8 (row-quantized)
    const signed char* __restrict__ W,   // [N][K] i8
    const float* __restrict__ s_a,       // [M] activation row scales
    const float* __restrict__ scale,     // [N] weight col scales
    const float* __restrict__ bias,      // [N]
    float* __restrict__ C,               // [M][N] f32
    int M, int N, int K) {
  __shared__ __align__(16) signed char As[2][2][128 * 128];  // 64 KiB
  __shared__ __align__(16) signed char Bs[2][2][128 * 128];  // 64 KiB

  const int tid = threadIdx.x;
  const int lane = tid & 63;
  const int wv = tid >> 6;       // 0..7
  const int wm = wv >> 2;        // 0..1  (wave rows: LDS half wm)
  const int wn = wv & 3;         // 0..3  (wave cols: 64 within B-half wn>>1)

  const int nwg = gridDim.x;
  const int bid = blockIdx.x;
  const int wg = ((nwg & 7) == 0) ? ((bid & 7) * (nwg >> 3) + (bid >> 3)) : bid;
  const int mT = M / BM;
  const int bm = wg % mT;        // M-fast: neighbors share W panel
  const int bn = wg / mT;

  const long aRow0 = (long)bm * BM;
  const long wRow0 = (long)bn * BN;

  // ---- staging (byte-identical to R16): issue q in {0,1}; 1KB per issue.
  const int sRow0 = (0 * 8 + wv) * 8 + (lane >> 3);
  const int sRow1 = (1 * 8 + wv) * 8 + (lane >> 3);
  const int srcslot = (lane & 7) ^ (((wv & 1) << 2) | (lane >> 4));
  const signed char* aS0 = A + (aRow0 + sRow0) * (long)K + srcslot * 16;
  const signed char* aS1 = A + (aRow0 + sRow1) * (long)K + srcslot * 16;
  const signed char* wS0 = W + (wRow0 + sRow0) * (long)K + srcslot * 16;
  const signed char* wS1 = W + (wRow0 + sRow1) * (long)K + srcslot * 16;
  const long AH = 128 * (long)K;           // second-half source row offset
  const int d0 = (0 * 8 + wv) * 1024 + lane * 16;
  const int d1 = (1 * 8 + wv) * 1024 + lane * 16;

  // ---- 32x32 read base: row (lane&31), phys slot ((lane>>5)^((lane>>1)&7));
  // kstep ks XORs slot bits 1-2 (disjoint from slot bit 0) -> byte ^ ks*32.
  const int rd32 = (lane & 31) * 128 + (((lane >> 5) ^ ((lane >> 1) & 7)) * 16);
  int rdx[4];
#pragma unroll
  for (int ks = 0; ks < 4; ++ks) rdx[ks] = rd32 ^ (ks * 32);
  const int rdBo = (wn & 1) * 8192;        // wave's 64 B-rows within its half

  iv16 acc[4][2] = {};
  iv4 aF[2][4], bQ0[4], bQ1[4];

  const int nk = K / BKB;   // 32

  // ---- prologue: t0 all 4 halves -> buf0; t1.B1, t1.A0 -> buf1
  GLDS16(aS0, &As[0][0][d0]);           GLDS16(aS1, &As[0][0][d1]);
  GLDS16(aS0 + AH, &As[0][1][d0]);      GLDS16(aS1 + AH, &As[0][1][d1]);
  GLDS16(wS0, &Bs[0][0][d0]);           GLDS16(wS1, &Bs[0][0][d1]);
  GLDS16(wS0 + AH, &Bs[0][1][d0]);      GLDS16(wS1 + AH, &Bs[0][1][d1]);
  GLDS16(wS0 + AH + BKB, &Bs[1][1][d0]); GLDS16(wS1 + AH + BKB, &Bs[1][1][d1]);
  GLDS16(aS0 + BKB, &As[1][0][d0]);     GLDS16(aS1 + BKB, &As[1][0][d1]);
  VMC_4;   // retire 8 oldest = all of t0; t1.{B1,A0} stay in flight
  BAR;

#define TILE_BODY(CUR, NXT, KO1, KO2)                                         \
  {                                                                           \
    lds_c8* pA[4];                                                            \
    lds_c8* pB[4];                                                            \
    _Pragma("unroll") for (int ks = 0; ks < 4; ++ks) {                        \
      pA[ks] = (lds_c8*)&As[CUR][wm][rdx[ks]];                                \
      pB[ks] = (lds_c8*)&Bs[CUR][wn >> 1][rdBo + rdx[ks]];                    \
    }                                                                         \
    /* ph1 (rows 0-63, cols 0-31): 12 reads; stage A1(t+1) */                 \
    bQ0[0] = ldsb128<0>(pB[0]); bQ0[1] = ldsb128<0>(pB[1]);                   \
    bQ0[2] = ldsb128<0>(pB[2]); bQ0[3] = ldsb128<0>(pB[3]);                   \
    aF[0][0] = ldsb128<0>(pA[0]);    aF[1][0] = ldsb128<4096>(pA[0]);         \
    aF[0][1] = ldsb128<0>(pA[1]);    aF[1][1] = ldsb128<4096>(pA[1]);         \
    aF[0][2] = ldsb128<0>(pA[2]);    aF[1][2] = ldsb128<4096>(pA[2]);         \
    aF[0][3] = ldsb128<0>(pA[3]);    aF[1][3] = ldsb128<4096>(pA[3]);         \
    GLDS16(aS0 + AH + (KO1), &As[NXT][1][d0]);                                \
    GLDS16(aS1 + AH + (KO1), &As[NXT][1][d1]);                                \
    LGKM_8; SCHEDB;                                                           \
    BAR;                                                                      \
    LGKM_0; SCHEDB;                                                           \
    __builtin_amdgcn_s_setprio(1);                                            \
    PH8(aF, bQ0, 0, 0);                                                       \
    __builtin_amdgcn_s_setprio(0);                                            \
    SCHEDB; BAR;                                                              \
    /* ph2 (rows 0-63, cols 32-63): 4 reads; stage B0(t+1) */                 \
    bQ1[0] = ldsb128<4096>(pB[0]); bQ1[1] = ldsb128<4096>(pB[1]);             \
    bQ1[2] = ldsb128<4096>(pB[2]); bQ1[3] = ldsb128<4096>(pB[3]);             \
    GLDS16(wS0 + (KO1), &Bs[NXT][0][d0]);                                     \
    GLDS16(wS1 + (KO1), &Bs[NXT][0][d1]);                                     \
    BAR;                                                                      \
    LGKM_0; SCHEDB;                                                           \
    __builtin_amdgcn_s_setprio(1);                                            \
    PH8(aF, bQ1, 0, 1);                                                       \
    __builtin_amdgcn_s_setprio(0);                                            \
    SCHEDB; BAR;                                                              \
    /* ph3 (rows 64-127, cols 32-63): 8 reads; stage B1(t+2) */               \
    aF[0][0] = ldsb128<8192>(pA[0]); aF[1][0] = ldsb128<12288>(pA[0]);        \
    aF[0][1] = ldsb128<8192>(pA[1]); aF[1][1] = ldsb128<12288>(pA[1]);        \
    aF[0][2] = ldsb128<8192>(pA[2]); aF[1][2] = ldsb128<12288>(pA[2]);        \
    aF[0][3] = ldsb128<8192>(pA[3]); aF[1][3] = ldsb128<12288>(pA[3]);        \
    GLDS16(wS0 + AH + (KO2), &Bs[CUR][1][d0]);                                \
    GLDS16(wS1 + AH + (KO2), &Bs[CUR][1][d1]);                                \
    BAR;                                                                      \
    LGKM_0; SCHEDB;                                                           \
    __builtin_amdgcn_s_setprio(1);                                            \
    PH8(aF, bQ1, 2, 1);                                                       \
    __builtin_amdgcn_s_setprio(0);                                            \
    SCHEDB; BAR;                                                              \
    /* ph4 (rows 64-127, cols 0-31): 0 reads; stage A0(t+2); vmcnt(4) */      \
    GLDS16(aS0 + (KO2), &As[CUR][0][d0]);                                     \
    GLDS16(aS1 + (KO2), &As[CUR][0][d1]);                                     \
    __builtin_amdgcn_s_setprio(1);                                            \
    PH8(aF, bQ0, 2, 0);                                                       \
    __builtin_amdgcn_s_setprio(0);                                            \
    VMC_4; SCHEDB;                                                            \
    BAR;                                                                      \
  }

  for (int kt = 0; kt < nk; kt += 2) {
    const long ka1 = (long)(kt + 1) * BKB;                        // < nk
    const long ka2 = (kt + 2 < nk) ? (long)(kt + 2) * BKB : 0;    // wrap ok
    const long kb1 = ka2;
    const long kb2 = (kt + 3 < nk) ? (long)(kt + 3) * BKB : 0;
    TILE_BODY(0, 1, ka1, ka2);
    TILE_BODY(1, 0, kb1, kb2);
  }
#undef TILE_BODY

  // ---- epilogue: 32x32 C/D layout col=lane&31,
  // row = (reg&3) + 8*(reg>>2) + 4*(lane>>5)  [m74/m101; dtype-indep]
  const long col0 = wRow0 + wn * 64 + (lane & 31);
  float scl[2], bs[2];
#pragma unroll
  for (int tj = 0; tj < 2; ++tj) {
    scl[tj] = scale[col0 + tj * 32];
    bs[tj] = bias[col0 + tj * 32];
  }
  const long row0 = aRow0 + wm * 128 + ((lane >> 5) << 2);
#pragma unroll
  for (int ti = 0; ti < 4; ++ti) {
#pragma unroll
    for (int q = 0; q < 4; ++q) {
      const long rbase = row0 + ti * 32 + q * 8;
#pragma unroll
      for (int r = 0; r < 4; ++r) {
        const long row = rbase + r;
        const float rs = s_a[row];
        float* cp = C + row * (long)N + col0;
#pragma unroll
        for (int tj = 0; tj < 2; ++tj)
          cp[tj * 32] = (float)acc[ti][tj][q * 4 + r] * (rs * scl[tj]) + bs[tj];
      }
    }
  }
}

// correctness-only fallback (reads original fp32/int32 inputs)
__global__ void naive_w8a16(const float* __restrict__ inp,
                            const int* __restrict__ qw,
                            const float* __restrict__ scale,
                            const float* __restrict__ bias,
                            float* __restrict__ out, long M, long N, long K) {
  long idx = (long)blockIdx.x * blockDim.x + threadIdx.x;
  if (idx >= M * N) return;
  long col = idx % N, row = idx / N;
  const float* a = inp + row * K;
  const int* w = qw + col * K;
  float s = 0.f;
  for (long k = 0; k < K; k += 4) {
    float4 av = *reinterpret_cast<const float4*>(&a[k]);
    int4 wv = *reinterpret_cast<const int4*>(&w[k]);
    s += av.x * (float)wv.x + av.y * (float)wv.y + av.z * (float)wv.z +
         av.w * (float)wv.w;
  }
  out[idx] = s * scale[col] + bias[col];
}

extern "C" void kernel_launch(void* const* d_in, const int* in_sizes, int n_in,
                              void* d_out, int out_size, void* d_ws,
                              size_t ws_size, hipStream_t stream) {
  const float* inp = (const float*)d_in[0];   // [B,S,D_IN] f32
  const int* qw = (const int*)d_in[1];        // [D_OUT,D_IN] i32
  const float* scale = (const float*)d_in[2]; // [D_OUT]
  const float* bias = (const float*)d_in[3];  // [D_OUT]
  float* out = (float*)d_out;                 // [B,S,D_OUT] f32

  const long N = in_sizes[2];                 // 16384
  const long K = (long)in_sizes[1] / N;       // 4096
  const long M = (long)in_sizes[0] / K;       // 8192

  const size_t aB = (size_t)M * K;            // 32 MiB (i8)
  const size_t wB = (size_t)N * K;            // 64 MiB (i8)
  const size_t sB = (size_t)M * 4;            // row scales
  const long nk = K / BKB;

  if (ws_size >= aB + wB + sB && (M % BM) == 0 && (N % BN) == 0 &&
      K == 4096 && nk >= 4 && (nk % 2) == 0) {
    signed char* Ai8 = (signed char*)d_ws;
    signed char* Wi8 = (signed char*)d_ws + aB;
    float* sA = (float*)((char*)d_ws + aB + wB);
    quant_act<<<(int)M, 256, 0, stream>>>(inp, Ai8, sA, (int)K);
    pack_w<<<2048, 256, 0, stream>>>(qw, Wi8, N * K / 16);
    const int nwg = (int)((M / BM) * (N / BN));  // 2048
    gemm256_m3<<<nwg, 512, 0, stream>>>(Ai8, Wi8, sA, scale, bias, out,
                                        (int)M, (int)N, (int)K);
  } else {
    long total = M * N;
    naive_w8a16<<<(int)((total + 255) / 256), 256, 0, stream>>>(
        inp, qw, scale, bias, out, M, N, K);
  }
}